// Round 2
// baseline (4186.187 us; speedup 1.0000x reference)
//
#include <hip/hip_runtime.h>

#define XD    64      // x_dim
#define HID   256     // hidden
#define G4    1024    // 4*hidden
#define TLEN  2048
#define BATCH 64
#define NPART 8       // blocks per chain
#define UPB   32      // hidden units per part
#define CPB   128     // gate columns per part (4 gates x 32 units)
#define TSTRIDE 16    // ints between chains' handshake-token groups (64B line)

typedef unsigned int uint;

__device__ __forceinline__ float sigmf(float x) {
    return 1.0f / (1.0f + __expf(-x));
}
// tanh(x) = 1 - 2/(exp(2x)+1); __expf saturation gives correct +/-1 tails
__device__ __forceinline__ float tanhfast(float x) {
    return 1.0f - 2.0f / (1.0f + __expf(2.0f * x));
}
// wave-uniform broadcast: lane value -> SGPR, feeds v_fma as the scalar operand.
// Replaces LDS broadcast (the old 1.07us/step LDS-return floor) with VALU issue.
__device__ __forceinline__ float rdl(float v, int l) {
    return __uint_as_float(__builtin_amdgcn_readlane(__float_as_uint(v), l));
}

// ---- fused (h, stamp) 8-byte pair transport ----------------------------
// fast path (parts verified same-XCD): sc0 = bypass CU L1, coherent at the
// shared per-XCD L2. nt: never allocate in L1 so polls can't go stale.
// Multi-load variants issue all loads BEFORE one vmcnt(0): one L2 round trip.
__device__ __forceinline__ void ld2_sc0(const uint2* p0, const uint2* p1,
                                        uint2& a, uint2& b) {
    asm volatile("global_load_dwordx2 %0, %2, off sc0 nt\n\t"
                 "global_load_dwordx2 %1, %3, off sc0 nt\n\t"
                 "s_waitcnt vmcnt(0)"
                 : "=&v"(a), "=&v"(b)
                 : "v"(p0), "v"(p1) : "memory");
}
__device__ __forceinline__ void ld3_sc0(const uint2* p0, const uint2* p1,
                                        const uint2* p2,
                                        uint2& a, uint2& b, uint2& c) {
    asm volatile("global_load_dwordx2 %0, %3, off sc0 nt\n\t"
                 "global_load_dwordx2 %1, %4, off sc0 nt\n\t"
                 "global_load_dwordx2 %2, %5, off sc0 nt\n\t"
                 "s_waitcnt vmcnt(0)"
                 : "=&v"(a), "=&v"(b), "=&v"(c)
                 : "v"(p0), "v"(p1), "v"(p2) : "memory");
}
__device__ __forceinline__ void st_pair_sc0(uint2* p, uint2 v) {
    asm volatile("global_store_dwordx2 %0, %1, off sc0" :: "v"(p), "v"(v) : "memory");
}
// slow path (parts on different XCDs): device-scope 8B atomics via LLC.
__device__ __forceinline__ uint2 ld_pair_dev(const uint2* p) {
    unsigned long long u = __hip_atomic_load((const unsigned long long*)p,
                                             __ATOMIC_RELAXED, __HIP_MEMORY_SCOPE_AGENT);
    uint2 r; r.x = (uint)(u & 0xffffffffu); r.y = (uint)(u >> 32); return r;
}
__device__ __forceinline__ void st_pair_dev(uint2* p, uint2 v) {
    unsigned long long u = ((unsigned long long)v.y << 32) | (unsigned long long)v.x;
    __hip_atomic_store((unsigned long long*)p, u, __ATOMIC_RELAXED, __HIP_MEMORY_SCOPE_AGENT);
}

// Zero pair stamps (both buffers) + handshake tokens. ws is re-poisoned to
// 0xAA before every timed call, so this must run every launch.
__global__ void init_ws(unsigned long long* __restrict__ pairs, int* __restrict__ tok) {
    const int i = blockIdx.x * 256 + threadIdx.x;       // 64 blocks x 256 thr
    pairs[i] = 0ULL;                                    // buffer 0
    pairs[BATCH * HID + i] = 0ULL;                      // buffer 1
    if (threadIdx.x < TSTRIDE) tok[blockIdx.x * TSTRIDE + threadIdx.x] = 0;
}

// 512 blocks = 64 chains x 8 parts, 256 threads, 2 blocks/CU.
// Chain-major decode: chain = blk&63, part = blk>>6 -> all parts share blk%8
// -> same XCD under round-robin dispatch (verified by runtime handshake).
// NEW vs r1: halves are WAVE-major. Waves 0,1 = half 0 (x[0:64]+h[0:96]) of
// columns 0..127; waves 2,3 = half 1 (h[96:256]). Operands are broadcast via
// v_readlane -> SGPR -> v_fma scalar operand: zero LDS operand traffic.
__global__ __launch_bounds__(256, 2)
void lstm_par(const float* __restrict__ x,     // (B, T, 64)
              const float* __restrict__ wih,   // (1024, 64) row-major
              const float* __restrict__ whh,   // (1024, 256) row-major
              const float* __restrict__ bias,  // (1024)
              float* __restrict__ out,         // (B, T, 256)
              uint2* __restrict__ pairs,       // (2, B, 256) {h_bits, stamp}
              int* __restrict__ tok)           // (B, TSTRIDE) handshake tokens
{
    const int b     = blockIdx.x & 63;          // chain
    const int part  = blockIdx.x >> 6;          // part
    const int tid   = threadIdx.x;
    const int lane  = tid & 63;
    const int wv    = tid >> 6;                 // wave 0..3
    const int halfw = wv >> 1;                  // waves 0,1 -> 0; 2,3 -> 1
    const int c     = ((wv & 1) << 6) | lane;   // column within part, 0..127
    const int q     = c >> 5;                   // gate index (i,f,g,o)
    const int u     = c & 31;                   // unit within part
    const int j     = q * 256 + part * UPB + u; // global gate column

    __shared__ float zsh[2][CPB];               // per-half z partials
    __shared__ int fastsh;

    // ---- one-time: weights into registers (amortized over 2048 steps) ----
    float4 w4[40];
    {
        const float4* wihr = (const float4*)(wih + (size_t)j * XD);
        const float4* whhr = (const float4*)(whh + (size_t)j * HID);
        if (halfw == 0) {
            #pragma unroll
            for (int i = 0; i < 16; ++i) w4[i] = wihr[i];        // w_ih[j][0:64]
            #pragma unroll
            for (int i = 0; i < 24; ++i) w4[16 + i] = whhr[i];   // w_hh[j][0:96]
        } else {
            #pragma unroll
            for (int i = 0; i < 40; ++i) w4[i] = whhr[24 + i];   // w_hh[j][96:256]
        }
    }
    const float bj = (halfw == 0) ? bias[j] : 0.0f;

    // ---- one-time XCD co-location handshake (device-scope, reliable) ----
    {
        int xcc;
        asm volatile("s_getreg_b32 %0, hwreg(HW_REG_XCC_ID)" : "=s"(xcc));
        xcc &= 15;
        int* tb = tok + b * TSTRIDE;
        if (tid == 0)
            __hip_atomic_store(tb + part, 256 + xcc, __ATOMIC_RELEASE,
                               __HIP_MEMORY_SCOPE_AGENT);
        if (tid < 64) {
            const int ln = tid & 7;            // 64 lanes cover 8 tokens
            int v = 0, guard = 0;
            for (;;) {
                v = __hip_atomic_load(tb + ln, __ATOMIC_RELAXED,
                                      __HIP_MEMORY_SCOPE_AGENT);
                if (__all(v >= 256)) break;
                __builtin_amdgcn_s_sleep(2);
                if (++guard > 200000) break;   // catastrophe-only
            }
            const int ok = __all(v >= 256);
            const int v0 = __shfl(v, 0);
            const int eq = (ok && __all(v == v0)) ? 1 : 0;
            if (tid == 0) fastsh = eq;
        }
        __syncthreads();
    }
    const bool fast = (fastsh != 0);

    uint2* __restrict__ pb0 = pairs + (size_t)b * HID;            // buffer 0
    uint2* __restrict__ pb1 = pairs + (size_t)(BATCH + b) * HID;  // buffer 1
    const float* __restrict__ xb = x + (size_t)b * TLEN * XD;
    float* __restrict__ ob = out + (size_t)b * TLEN * HID;

    float cst = 0.0f;                     // thread tid<32 owns cell of unit tid
    float xreg = (halfw == 0) ? xb[lane] : 0.0f;   // x_0 (lane l holds x[l])

    for (int t = 0; t < TLEN; ++t) {
        // ---- gather h_{t-1} slices into lane registers (no LDS staging) ----
        float h0 = 0.f, h1 = 0.f, hA = 0.f, hB = 0.f, hC = 0.f;
        if (t > 0) {
            const uint2* src = ((t & 1) ? pb0 : pb1);   // buf (t-1)&1
            if (halfw == 0) {
                // lane l: h[l] and h[64+(l&31)]  (lanes 0..31 carry h[64:96))
                const uint2* p0 = src + lane;
                const uint2* p1 = src + 64 + (lane & 31);
                uint2 a, bb;
                int it = 0;
                for (;;) {
                    if (fast && it < 4096) ld2_sc0(p0, p1, a, bb);
                    else { a = ld_pair_dev(p0); bb = ld_pair_dev(p1); }
                    if (__all(a.y == (uint)t && bb.y == (uint)t)) break;
                    __builtin_amdgcn_s_sleep(1);
                    if (++it > 100000) break;  // hang-guard: corrupt, don't hang
                }
                h0 = __uint_as_float(a.x);
                h1 = __uint_as_float(bb.x);
            } else {
                // lane l: h[96+l], h[160+l], h[224+(l&31)]
                const uint2* p0 = src + 96 + lane;
                const uint2* p1 = src + 160 + lane;
                const uint2* p2 = src + 224 + (lane & 31);
                uint2 a, bb, cc;
                int it = 0;
                for (;;) {
                    if (fast && it < 4096) ld3_sc0(p0, p1, p2, a, bb, cc);
                    else { a = ld_pair_dev(p0); bb = ld_pair_dev(p1); cc = ld_pair_dev(p2); }
                    if (__all(a.y == (uint)t && bb.y == (uint)t && cc.y == (uint)t)) break;
                    __builtin_amdgcn_s_sleep(1);
                    if (++it > 100000) break;
                }
                hA = __uint_as_float(a.x);
                hB = __uint_as_float(bb.x);
                hC = __uint_as_float(cc.x);
            }
        }

        // prefetch next x early (latency hidden under the FMA stream)
        float xnext = 0.f;
        if (halfw == 0 && t + 1 < TLEN) xnext = xb[(size_t)(t + 1) * XD + lane];

        // ---- 160-dim half-dot: register weights x readlane-broadcast operands
        float4 acc = make_float4(bj, 0.f, 0.f, 0.f);
        #define FMA4(W, SRC, BASE)                                   \
            acc.x = fmaf((W).x, rdl((SRC), (BASE) + 0), acc.x);      \
            acc.y = fmaf((W).y, rdl((SRC), (BASE) + 1), acc.y);      \
            acc.z = fmaf((W).z, rdl((SRC), (BASE) + 2), acc.z);      \
            acc.w = fmaf((W).w, rdl((SRC), (BASE) + 3), acc.w);
        if (halfw == 0) {
            #pragma unroll
            for (int i = 0; i < 16; ++i) { FMA4(w4[i],      xreg, 4 * i) } // x[0:64)
            #pragma unroll
            for (int i = 0; i < 16; ++i) { FMA4(w4[16 + i], h0,   4 * i) } // h[0:64)
            #pragma unroll
            for (int i = 0; i < 8;  ++i) { FMA4(w4[32 + i], h1,   4 * i) } // h[64:96)
        } else {
            #pragma unroll
            for (int i = 0; i < 16; ++i) { FMA4(w4[i],      hA,   4 * i) } // h[96:160)
            #pragma unroll
            for (int i = 0; i < 16; ++i) { FMA4(w4[16 + i], hB,   4 * i) } // h[160:224)
            #pragma unroll
            for (int i = 0; i < 8;  ++i) { FMA4(w4[32 + i], hC,   4 * i) } // h[224:256)
        }
        #undef FMA4
        xreg = xnext;
        const float z = (acc.x + acc.y) + (acc.z + acc.w);
        zsh[halfw][c] = z;
        __syncthreads();  // single barrier per step: orders zsh writes vs reads;
                          // next-step zsh overwrites are gated by the recurrence
                          // (any wave's step t+1 requires wave 0's publish at t,
                          // which follows wave 0's zsh reads in program order).

        // ---- gates, state update, publish (threads 0..31; all in wave 0) ----
        if (tid < UPB) {
            const float zi = zsh[0][tid]          + zsh[1][tid];
            const float zf = zsh[0][32 + tid]     + zsh[1][32 + tid];
            const float zg = zsh[0][64 + tid]     + zsh[1][64 + tid];
            const float zo = zsh[0][96 + tid]     + zsh[1][96 + tid];
            const float ig = sigmf(zi);
            const float fg = sigmf(zf);
            const float gg = tanhfast(zg);
            const float og = sigmf(zo);
            cst = fg * cst + ig * gg;
            const float h = og * tanhfast(cst);
            // fused publish: stamp travels WITH the value (single 8B store)
            uint2 pv; pv.x = __float_as_uint(h); pv.y = (uint)(t + 1);
            uint2* dst = ((t & 1) ? pb1 : pb0) + part * UPB + tid;
            if (fast) st_pair_sc0(dst, pv);
            else      st_pair_dev(dst, pv);
            // output store AFTER the publish: off the inter-part critical path
            ob[(size_t)t * HID + part * UPB + tid] = h;
        }
    }
}

extern "C" void kernel_launch(void* const* d_in, const int* in_sizes, int n_in,
                              void* d_out, int out_size, void* d_ws, size_t ws_size,
                              hipStream_t stream) {
    const float* x    = (const float*)d_in[0];
    const float* wih  = (const float*)d_in[1];
    const float* whh  = (const float*)d_in[2];
    const float* bias = (const float*)d_in[3];
    float* out = (float*)d_out;

    uint2* pairs = (uint2*)d_ws;  // 2*64*256 pairs = 256 KB
    int*   tok   = (int*)((char*)d_ws + (size_t)2 * BATCH * HID * sizeof(uint2)); // 4 KB

    hipLaunchKernelGGL(init_ws, dim3(BATCH), dim3(256), 0, stream,
                       (unsigned long long*)d_ws, tok);
    hipLaunchKernelGGL(lstm_par, dim3(BATCH * NPART), dim3(256), 0, stream,
                       x, wih, whh, bias, out, pairs, tok);
}

// Round 3
// 2758.658 us; speedup vs baseline: 1.5175x; 1.5175x over previous
//
#include <hip/hip_runtime.h>

#define XD    64      // x_dim
#define HID   256     // hidden
#define G4    1024    // 4*hidden
#define TLEN  2048
#define BATCH 64
#define NPART 8       // blocks per chain
#define UPB   32      // hidden units per part
#define CPB   128     // gate columns per part (4 gates x 32 units)
#define TSTRIDE 16    // ints between chains' handshake-token groups (64B line)

typedef unsigned int uint;

__device__ __forceinline__ float sigmf(float x) {
    return 1.0f / (1.0f + __expf(-x));
}
// tanh(x) = 1 - 2/(exp(2x)+1); __expf saturation gives correct +/-1 tails
__device__ __forceinline__ float tanhfast(float x) {
    return 1.0f - 2.0f / (1.0f + __expf(2.0f * x));
}

// ---- fused (h, stamp) 8-byte pair transport ----------------------------
// fast path (parts verified same-XCD): sc0 = bypass CU L1, coherent at the
// shared per-XCD L2. nt: never allocate in L1 so polls can't go stale.
__device__ __forceinline__ uint2 ld_pair_sc0(const uint2* p) {
    uint2 r;
    asm volatile("global_load_dwordx2 %0, %1, off sc0 nt\n\ts_waitcnt vmcnt(0)"
                 : "=v"(r) : "v"(p) : "memory");
    return r;
}
__device__ __forceinline__ void st_pair_sc0(uint2* p, uint2 v) {
    asm volatile("global_store_dwordx2 %0, %1, off sc0" :: "v"(p), "v"(v) : "memory");
}
// slow path (parts on different XCDs): device-scope 8B atomics via LLC.
__device__ __forceinline__ uint2 ld_pair_dev(const uint2* p) {
    unsigned long long u = __hip_atomic_load((const unsigned long long*)p,
                                             __ATOMIC_RELAXED, __HIP_MEMORY_SCOPE_AGENT);
    uint2 r; r.x = (uint)(u & 0xffffffffu); r.y = (uint)(u >> 32); return r;
}
__device__ __forceinline__ void st_pair_dev(uint2* p, uint2 v) {
    unsigned long long u = ((unsigned long long)v.y << 32) | (unsigned long long)v.x;
    __hip_atomic_store((unsigned long long*)p, u, __ATOMIC_RELAXED, __HIP_MEMORY_SCOPE_AGENT);
}

// Zero pair stamps (both buffers) + handshake tokens. ws is re-poisoned to
// 0xAA before every timed call, so this must run every launch.
__global__ void init_ws(unsigned long long* __restrict__ pairs, int* __restrict__ tok) {
    const int i = blockIdx.x * 256 + threadIdx.x;       // 64 blocks x 256 thr
    pairs[i] = 0ULL;                                    // buffer 0
    pairs[BATCH * HID + i] = 0ULL;                      // buffer 1
    if (threadIdx.x < TSTRIDE) tok[blockIdx.x * TSTRIDE + threadIdx.x] = 0;
}

// 512 blocks = 64 chains x 8 parts, 256 threads, 2 blocks/CU.
// Chain-major decode: chain = blk&63, part = blk>>6 -> all parts share blk%8
// -> same XCD under round-robin dispatch (verified by runtime handshake).
//
// NEW vs r1: 4-column operand reuse. Thread t = (slice s = t>>5, quad cq =
// t&31) owns output columns 4cq..4cq+3 and operand elements [40s, 40s+40) of
// the combined 320-vector [x_t | h_{t-1}]. Each LDS operand element feeds 4
// FMAs (was 1) -> ds_read_b128 per CU-step drops 320 -> 80. Weights held
// transposed: w4[e] = {w[c0][e], w[c1][e], w[c2][e], w[c3][e]}.
// Reduction: shfl_xor(32) pairs slices within a wave, then zp[4][128] in LDS,
// gate wave sums 4 partials per column.
__global__ __launch_bounds__(256, 2)
void lstm_par(const float* __restrict__ x,     // (B, T, 64)
              const float* __restrict__ wih,   // (1024, 64) row-major
              const float* __restrict__ whh,   // (1024, 256) row-major
              const float* __restrict__ bias,  // (1024)
              float* __restrict__ out,         // (B, T, 256)
              uint2* __restrict__ pairs,       // (2, B, 256) {h_bits, stamp}
              int* __restrict__ tok)           // (B, TSTRIDE) handshake tokens
{
    const int b    = blockIdx.x & 63;          // chain
    const int part = blockIdx.x >> 6;          // part
    const int tid  = threadIdx.x;
    const int lane = tid & 63;
    const int wv   = tid >> 6;                 // wave 0..3
    const int s    = tid >> 5;                 // operand slice 0..7 (40 elems)
    const int cq   = tid & 31;                 // column quad: cols 4cq..4cq+3

    __shared__ __align__(16) float vec[XD + HID]; // [x_t | h_{t-1}]
    __shared__ __align__(16) float zp[4][CPB];    // per-wave-pair z partials
    __shared__ int fastsh;

    // ---- one-time: transposed weights into registers ----
    // w4[e] = weights of the thread's 4 columns at combined-element 40s+e.
    float4 w4[40];
    {
        int jr[4];
        #pragma unroll
        for (int k = 0; k < 4; ++k) {
            const int c = 4 * cq + k;                       // col within part
            jr[k] = (c >> 5) * 256 + part * UPB + (c & 31); // global gate row
        }
        #pragma unroll
        for (int e = 0; e < 40; ++e) {
            const int ge = s * 40 + e;                      // 0..319
            float v0, v1, v2, v3;
            if (ge < XD) {
                v0 = wih[jr[0] * XD + ge]; v1 = wih[jr[1] * XD + ge];
                v2 = wih[jr[2] * XD + ge]; v3 = wih[jr[3] * XD + ge];
            } else {
                const int he = ge - XD;
                v0 = whh[jr[0] * HID + he]; v1 = whh[jr[1] * HID + he];
                v2 = whh[jr[2] * HID + he]; v3 = whh[jr[3] * HID + he];
            }
            w4[e] = make_float4(v0, v1, v2, v3);
        }
    }
    // gate-wave bias preload (threads 0..31: unit u = tid)
    float bi = 0.f, bf = 0.f, bg = 0.f, bo = 0.f;
    if (tid < UPB) {
        const int gj = part * UPB + tid;
        bi = bias[gj]; bf = bias[256 + gj]; bg = bias[512 + gj]; bo = bias[768 + gj];
    }

    // ---- one-time XCD co-location handshake (device-scope, reliable) ----
    {
        int xcc;
        asm volatile("s_getreg_b32 %0, hwreg(HW_REG_XCC_ID)" : "=s"(xcc));
        xcc &= 15;
        int* tb = tok + b * TSTRIDE;
        if (tid == 0)
            __hip_atomic_store(tb + part, 256 + xcc, __ATOMIC_RELEASE,
                               __HIP_MEMORY_SCOPE_AGENT);
        if (tid < 64) {
            const int ln = tid & 7;            // 64 lanes cover 8 tokens
            int v = 0, guard = 0;
            for (;;) {
                v = __hip_atomic_load(tb + ln, __ATOMIC_RELAXED,
                                      __HIP_MEMORY_SCOPE_AGENT);
                if (__all(v >= 256)) break;
                __builtin_amdgcn_s_sleep(2);
                if (++guard > 200000) break;   // catastrophe-only
            }
            const int ok = __all(v >= 256);
            const int v0 = __shfl(v, 0);
            const int eq = (ok && __all(v == v0)) ? 1 : 0;
            if (tid == 0) fastsh = eq;
        }
        __syncthreads();
    }
    const bool fast = (fastsh != 0);

    uint2* __restrict__ pb0 = pairs + (size_t)b * HID;            // buffer 0
    uint2* __restrict__ pb1 = pairs + (size_t)(BATCH + b) * HID;  // buffer 1
    const float* __restrict__ xb = x + (size_t)b * TLEN * XD;
    float* __restrict__ ob = out + (size_t)b * TLEN * HID;

    float cst = 0.0f;                     // thread tid<32 owns cell of unit tid
    float xreg = (tid < XD) ? xb[tid] : 0.0f;   // x_0 prefetch

    for (int t = 0; t < TLEN; ++t) {
        // ---- gather h_{t-1}: each thread polls ITS fused pair (stamp rides
        // with the data: one L2 leg) then stages into LDS.
        if (t > 0) {
            const uint2* src = ((t & 1) ? pb0 : pb1) + tid;  // buf (t-1)&1
            uint2 pr;
            int it = 0;
            for (;;) {
                pr = (fast && it < 4096) ? ld_pair_sc0(src) : ld_pair_dev(src);
                if (pr.y == (uint)t) break;   // exact-match: deadlock (visible
                __builtin_amdgcn_s_sleep(1);  // failure) over silent staleness
                if (++it > 100000) break;     // hang-guard: corrupt, don't hang
            }
            vec[XD + tid] = __uint_as_float(pr.x);
        } else {
            vec[XD + tid] = 0.0f;             // h_{-1} = 0
        }
        if (tid < XD) vec[tid] = xreg;
        __syncthreads(); // (B) -- also protects vec/zp from next-step overwrite

        // prefetch next x (latency overlapped by compute + next poll)
        if (t + 1 < TLEN && tid < XD) xreg = xb[(size_t)(t + 1) * XD + tid];

        // ---- 40-element slice x 4 columns: 10 ds_read_b128, 160 FMA ----
        float4 acc = make_float4(0.f, 0.f, 0.f, 0.f);
        const float4* vb = (const float4*)(vec + 40 * s);
        #pragma unroll
        for (int i = 0; i < 10; ++i) {
            const float4 v = vb[i];
            #define FMA1(R, VE)                              \
                acc.x = fmaf(w4[4*i + R].x, (VE), acc.x);    \
                acc.y = fmaf(w4[4*i + R].y, (VE), acc.y);    \
                acc.z = fmaf(w4[4*i + R].z, (VE), acc.z);    \
                acc.w = fmaf(w4[4*i + R].w, (VE), acc.w);
            FMA1(0, v.x) FMA1(1, v.y) FMA1(2, v.z) FMA1(3, v.w)
            #undef FMA1
        }
        // combine slice pairs (lane l <-> l^32 hold slices 2wv, 2wv+1)
        acc.x += __shfl_xor(acc.x, 32);
        acc.y += __shfl_xor(acc.y, 32);
        acc.z += __shfl_xor(acc.z, 32);
        acc.w += __shfl_xor(acc.w, 32);
        if (lane < 32) *(float4*)(&zp[wv][4 * lane]) = acc;
        __syncthreads(); // (C)

        // ---- gates, state update, publish (threads 0..31; all in wave 0) ----
        if (tid < UPB) {
            float zi = bi, zf = bf, zg = bg, zo = bo;
            #pragma unroll
            for (int w2 = 0; w2 < 4; ++w2) {
                zi += zp[w2][tid];            // col c = 0*32 + tid (gate i)
                zf += zp[w2][32 + tid];       // gate f
                zg += zp[w2][64 + tid];       // gate g
                zo += zp[w2][96 + tid];       // gate o
            }
            const float ig = sigmf(zi);
            const float fg = sigmf(zf);
            const float gg = tanhfast(zg);
            const float og = sigmf(zo);
            cst = fg * cst + ig * gg;
            const float h = og * tanhfast(cst);
            // fused publish: stamp travels WITH the value (single 8B store)
            uint2 pv; pv.x = __float_as_uint(h); pv.y = (uint)(t + 1);
            uint2* dst = ((t & 1) ? pb1 : pb0) + part * UPB + tid;
            if (fast) st_pair_sc0(dst, pv);
            else      st_pair_dev(dst, pv);
            // output store AFTER the publish: off the inter-part critical path
            ob[(size_t)t * HID + part * UPB + tid] = h;
        }
    }
}

extern "C" void kernel_launch(void* const* d_in, const int* in_sizes, int n_in,
                              void* d_out, int out_size, void* d_ws, size_t ws_size,
                              hipStream_t stream) {
    const float* x    = (const float*)d_in[0];
    const float* wih  = (const float*)d_in[1];
    const float* whh  = (const float*)d_in[2];
    const float* bias = (const float*)d_in[3];
    float* out = (float*)d_out;

    uint2* pairs = (uint2*)d_ws;  // 2*64*256 pairs = 256 KB
    int*   tok   = (int*)((char*)d_ws + (size_t)2 * BATCH * HID * sizeof(uint2)); // 4 KB

    hipLaunchKernelGGL(init_ws, dim3(BATCH), dim3(256), 0, stream,
                       (unsigned long long*)d_ws, tok);
    hipLaunchKernelGGL(lstm_par, dim3(BATCH * NPART), dim3(256), 0, stream,
                       x, wih, whh, bias, out, pairs, tok);
}